// Round 3
// baseline (922.662 us; speedup 1.0000x reference)
//
#include <hip/hip_runtime.h>
#include <stdint.h>

// Problem constants (reference: B=2, C=4, SPATIAL=(128,128,128), N_PTS=32, THR=0.5)
#define Bn 2
#define Cn 4
#define Sn (128 * 128 * 128)   // 2^21 voxels per (b,c)
#define NPTS 32
#define NBINS 1025             // probs in (0.5, 1] -> one binade; (bits-0x3F000000)>>13 in [0,1024]
#define THRf 0.5f
#define PB 4096                // voxels per block in the fused pass
#define SELCAP 8192            // LDS filtered-candidate cap in select2

__device__ __forceinline__ int bin_of_bits(unsigned int u) {
    return (int)((u - 0x3F000000u) >> 13);
}

// Softmax over the 4 classes at one voxel given the 4 logits; returns argmax class and its prob.
// Mirrors jax.nn.softmax: exp(x - max) / sum(exp(x - max)), sequential sum c=0..3.
// (Only the argmax class can have p > 0.5 since probs sum to 1.)
__device__ __forceinline__ void softmax_argmax4(float l0, float l1, float l2, float l3,
                                                int* cm_out, float* p_out) {
    float m = fmaxf(fmaxf(l0, l1), fmaxf(l2, l3));
    float e0 = expf(l0 - m);
    float e1 = expf(l1 - m);
    float e2 = expf(l2 - m);
    float e3 = expf(l3 - m);
    float s = ((e0 + e1) + e2) + e3;
    float em = e0; int cm = 0;
    if (e1 > em) { em = e1; cm = 1; }
    if (e2 > em) { em = e2; cm = 2; }
    if (e3 > em) { em = e3; cm = 3; }
    *cm_out = cm;
    *p_out = em / s;   // identical float division to reference's p_c = e_c / s
}

// Fused single-read pass:
//  phase 1: stream 4096 voxels (float4 x 4 class streams), cache candidates (p>0.5)
//           in LDS, build per-class local radix histogram in LDS.
//  phase 2: per-class local cutoff (wave w handles class w; shuffle suffix-scan).
//           Entries below the local cutoff have >=32 strictly-greater local entries
//           -> global rank >= 32 -> safe to drop. Union over blocks is a superset
//           of the global top-32 per (b,c).
//  phase 3: emit filtered candidates to global per-(b,c) buffers (atomic append).
__global__ __launch_bounds__(256) void fused_kernel(const float* __restrict__ logits,
                                                    unsigned int* __restrict__ cnt,
                                                    uint2* __restrict__ cand,
                                                    int cap) {
    __shared__ unsigned int lh[Cn * NBINS];   // 16.4 KB
    __shared__ uint2 buf[PB];                 // 32 KB  (max 1 candidate per voxel)
    __shared__ unsigned int ccount;
    __shared__ unsigned int lcut[Cn];
    const int b = blockIdx.y;
    const int t = threadIdx.x;
    for (int j = t; j < Cn * NBINS; j += 256) lh[j] = 0u;
    if (t == 0) ccount = 0u;
    if (t < Cn) lcut[t] = 0u;
    __syncthreads();

    const float* base = logits + (size_t)b * Cn * Sn;
    const float4* s0 = (const float4*)base;
    const float4* s1 = (const float4*)(base + Sn);
    const float4* s2 = (const float4*)(base + 2 * Sn);
    const float4* s3 = (const float4*)(base + 3 * Sn);
    const int qs = blockIdx.x * (PB / 4);
    #pragma unroll
    for (int it = 0; it < PB / 4 / 256; ++it) {   // 4 iterations
        int q = qs + it * 256 + t;
        float4 v0 = s0[q], v1 = s1[q], v2 = s2[q], v3 = s3[q];
        const float* a0 = &v0.x; const float* a1 = &v1.x;
        const float* a2 = &v2.x; const float* a3 = &v3.x;
        #pragma unroll
        for (int k = 0; k < 4; ++k) {
            int cm; float p;
            softmax_argmax4(a0[k], a1[k], a2[k], a3[k], &cm, &p);
            if (p > THRf) {
                unsigned int ub = __float_as_uint(p);
                atomicAdd(&lh[cm * NBINS + bin_of_bits(ub)], 1u);
                unsigned int pos = atomicAdd(&ccount, 1u);
                // idx fits in 21 bits (Sn = 2^21); class in bits 21-22
                buf[pos] = make_uint2(ub, (unsigned int)(q * 4 + k) | ((unsigned int)cm << 21));
            }
        }
    }
    __syncthreads();

    // phase 2: wave w computes cutoff for class w. 64 lanes x 17 bins = 1088 >= 1025.
    {
        const int wave = t >> 6, lane = t & 63;
        const unsigned int* h = &lh[wave * NBINS];
        const int lo = lane * 17;
        unsigned int cs = 0;
        #pragma unroll
        for (int k = 0; k < 17; ++k) {
            int bin = lo + k;
            if (bin < NBINS) cs += h[bin];
        }
        unsigned int S = cs;  // inclusive suffix sum over lanes (lane..63)
        #pragma unroll
        for (int off = 1; off < 64; off <<= 1) {
            unsigned int v = __shfl_down(S, off, 64);
            if (lane + off < 64) S += v;
        }
        unsigned int suf = S - cs;  // sum of bins strictly above this lane's chunk
        if (S >= NPTS && suf < NPTS) {
            unsigned int acc = suf;
            int hi = min(lo + 16, NBINS - 1);
            for (int bin = hi; bin >= lo; --bin) {
                acc += h[bin];
                if (acc >= NPTS) { lcut[wave] = (unsigned int)bin; break; }
            }
        }
        // if class total < 32, no lane fires and lcut stays 0 (emit all)
    }
    __syncthreads();

    // phase 3: emit candidates with bin >= local cutoff
    const unsigned int n = ccount;
    for (unsigned int j = t; j < n; j += 256) {
        uint2 e = buf[j];
        unsigned int cm = e.y >> 21;
        if ((unsigned int)bin_of_bits(e.x) >= lcut[cm]) {
            int bc = b * Cn + (int)cm;
            unsigned int pos = atomicAdd(&cnt[bc], 1u);
            if (pos < (unsigned int)cap)
                cand[(size_t)bc * cap + pos] = make_uint2(e.x, e.y & 0x1FFFFFu);
        }
    }
}

// Exact top-32 per (b,c) from the collected superset.
// The superset's histogram yields the exact global cutoff bin (all entries in
// strictly higher bins have global rank < 32 and are therefore all present).
// Ranking within the filtered superset is exact for top-32 members.
__global__ __launch_bounds__(256) void select2(const unsigned int* __restrict__ cnt,
                                               const uint2* __restrict__ cand,
                                               int cap,
                                               unsigned int* __restrict__ validn,
                                               uint2* __restrict__ topk) {
    __shared__ unsigned int lh[NBINS];
    __shared__ uint2 buf[SELCAP];
    __shared__ unsigned int mcnt;
    __shared__ unsigned int s_T;
    const int bc = blockIdx.x, t = threadIdx.x;
    const int n = min((int)cnt[bc], cap);
    for (int j = t; j < NBINS; j += 256) lh[j] = 0u;
    if (t == 0) { mcnt = 0u; s_T = 0u; }
    __syncthreads();
    const uint2* src = cand + (size_t)bc * cap;
    for (int j = t; j < n; j += 256)
        atomicAdd(&lh[bin_of_bits(src[j].x)], 1u);
    __syncthreads();
    if (t < 64) {  // wave 0: cutoff scan
        const int lane = t;
        const int lo = lane * 17;
        unsigned int cs = 0;
        #pragma unroll
        for (int k = 0; k < 17; ++k) {
            int bin = lo + k;
            if (bin < NBINS) cs += lh[bin];
        }
        unsigned int S = cs;
        #pragma unroll
        for (int off = 1; off < 64; off <<= 1) {
            unsigned int v = __shfl_down(S, off, 64);
            if (lane + off < 64) S += v;
        }
        unsigned int suf = S - cs;
        if (S >= NPTS && suf < NPTS) {
            unsigned int acc = suf;
            int hi = min(lo + 16, NBINS - 1);
            for (int bin = hi; bin >= lo; --bin) {
                acc += lh[bin];
                if (acc >= NPTS) { s_T = (unsigned int)bin; break; }
            }
        }
    }
    __syncthreads();
    const unsigned int T = s_T;
    for (int j = t; j < n; j += 256) {
        uint2 e = src[j];
        if ((unsigned int)bin_of_bits(e.x) >= T) {
            unsigned int pos = atomicAdd(&mcnt, 1u);
            if (pos < SELCAP) buf[pos] = e;
        }
    }
    __syncthreads();
    const int m = min((int)mcnt, SELCAP);
    const int vn = min(n, NPTS);
    if (t == 0) validn[bc] = (unsigned int)vn;
    for (int i = t; i < m; i += 256) {
        uint2 e = buf[i];
        int rank = 0;
        for (int j = 0; j < m; ++j) {
            uint2 o = buf[j];
            rank += (int)((o.x > e.x) || (o.x == e.x && o.y < e.y));
        }
        if (rank < vn) topk[bc * NPTS + rank] = e;
    }
}

// Compact per-batch in class order [1,2,3,0], unravel coords, pad with -1/0.
// Output layout: coords int32 (2,128,3) flat, then labels int32 (2,128).
__global__ void emit_kernel(const uint2* __restrict__ topk,
                            const unsigned int* __restrict__ validn,
                            int* __restrict__ out) {
    const int b = blockIdx.x;
    __shared__ int pre[Cn + 1];
    if (threadIdx.x == 0) {
        int acc = 0;
        for (int oc = 0; oc < Cn; ++oc) {
            pre[oc] = acc;
            int c = (oc + 1) & 3;  // order = [1,2,3,0]
            acc += (int)validn[b * Cn + c];
        }
        pre[Cn] = acc;
    }
    __syncthreads();
    const int j = threadIdx.x;  // 0..127
    int label = -1, z = 0, y = 0, x = 0;
    if (j < pre[Cn]) {
        int oc = 0;
        while (j >= pre[oc + 1]) ++oc;
        int c = (oc + 1) & 3;
        int r = j - pre[oc];
        uint2 e = topk[(b * Cn + c) * NPTS + r];
        int idx = (int)e.y;
        z = idx >> 14;          // idx / (128*128)
        y = (idx >> 7) & 127;   // (idx / 128) % 128
        x = idx & 127;          // idx % 128
        label = c;
    }
    int* coords = out;                       // 2*128*3 = 768 ints
    int* labels = out + Bn * Cn * NPTS * 3;  // then 2*128 = 256 ints
    int base = b * Cn * NPTS + j;
    coords[base * 3 + 0] = z;
    coords[base * 3 + 1] = y;
    coords[base * 3 + 2] = x;
    labels[base] = label;
}

extern "C" void kernel_launch(void* const* d_in, const int* in_sizes, int n_in,
                              void* d_out, int out_size, void* d_ws, size_t ws_size,
                              hipStream_t stream) {
    const float* logits = (const float*)d_in[0];
    int* out = (int*)d_out;

    // Workspace layout
    unsigned int* cnt = (unsigned int*)d_ws;             // 8 u32
    unsigned int* validn = cnt + Bn * Cn;                // 8 u32
    uint2* topk = (uint2*)(validn + Bn * Cn);            // 8*32 uint2 = 2048 B
    uint2* cand = topk + Bn * Cn * NPTS;                 // 8 * cap uint2
    size_t fixed = (size_t)((char*)cand - (char*)d_ws);
    int cap = (int)((ws_size - fixed) / (Bn * Cn * sizeof(uint2)));
    if (cap > (1 << 18)) cap = 1 << 18;   // 256k entries/bc is vastly more than the ~17k expected
    if (cap < 4096) cap = 4096;

    // Zero the 8 append counters only (capture-legal, stream-ordered)
    hipMemsetAsync(cnt, 0, Bn * Cn * sizeof(unsigned int), stream);

    dim3 grid(Sn / PB, Bn);   // (512, 2)
    fused_kernel<<<grid, 256, 0, stream>>>(logits, cnt, cand, cap);
    select2<<<Bn * Cn, 256, 0, stream>>>(cnt, cand, cap, validn, topk);
    emit_kernel<<<Bn, 128, 0, stream>>>(topk, validn, out);
}

// Round 4
// 231.545 us; speedup vs baseline: 3.9848x; 3.9848x over previous
//
#include <hip/hip_runtime.h>
#include <stdint.h>

// Problem constants (reference: B=2, C=4, SPATIAL=(128,128,128), N_PTS=32, THR=0.5)
#define Bn 2
#define Cn 4
#define Sn (128 * 128 * 128)   // 2^21 voxels per (b,c)
#define NPTS 32
#define NBINS 1025             // probs in (0.5, 1] -> one binade; (bits-0x3F000000)>>13 in [0,1024]
#define THRf 0.5f
#define PB 4096                // voxels per block in the fused pass
#define FCAP 2048              // LDS filtered-candidate cap in finish_kernel

__device__ __forceinline__ int bin_of_bits(unsigned int u) {
    return (int)((u - 0x3F000000u) >> 13);
}

// Softmax over the 4 classes at one voxel given the 4 logits; returns argmax class and its prob.
// Mirrors jax.nn.softmax: exp(x - max) / sum(exp(x - max)), sequential sum c=0..3.
// (Only the argmax class can have p > 0.5 since probs sum to 1.)
__device__ __forceinline__ void softmax_argmax4(float l0, float l1, float l2, float l3,
                                                int* cm_out, float* p_out) {
    float m = fmaxf(fmaxf(l0, l1), fmaxf(l2, l3));
    float e0 = expf(l0 - m);
    float e1 = expf(l1 - m);
    float e2 = expf(l2 - m);
    float e3 = expf(l3 - m);
    float s = ((e0 + e1) + e2) + e3;
    float em = e0; int cm = 0;
    if (e1 > em) { em = e1; cm = 1; }
    if (e2 > em) { em = e2; cm = 2; }
    if (e3 > em) { em = e3; cm = 3; }
    *cm_out = cm;
    *p_out = em / s;   // identical float division to reference's p_c = e_c / s
}

// Fused single-read pass:
//  phase 1: stream 4096 voxels (float4 x 4 class streams), cache candidates (p>0.5)
//           in LDS, build per-class local radix histogram in LDS.
//  phase 2: per-class local cutoff (wave w handles class w; shuffle suffix-scan).
//           Entries below the local cutoff have >=32 strictly-greater local entries
//           -> global rank >= 32 -> safe to drop. Union over blocks is a superset
//           of the global top-32 per (b,c).
//  phase 3: block-aggregated emit — count passing entries per class, ONE global
//           atomicAdd per (block,class) to reserve a range, then write entries.
//           (Per-entry same-address device atomics were the round-3 stall: 135k
//           serialized fetch-adds on 8 addresses = ~800 us.)
__global__ __launch_bounds__(256) void fused_kernel(const float* __restrict__ logits,
                                                    unsigned int* __restrict__ cnt,
                                                    uint2* __restrict__ cand,
                                                    int cap) {
    __shared__ unsigned int lh[Cn * NBINS];   // 16.4 KB
    __shared__ uint2 buf[PB];                 // 32 KB  (max 1 candidate per voxel)
    __shared__ unsigned int ccount;
    __shared__ unsigned int lcut[Cn];
    __shared__ unsigned int cls_cnt[Cn], cls_base[Cn], cls_pos[Cn];
    const int b = blockIdx.y;
    const int t = threadIdx.x;
    for (int j = t; j < Cn * NBINS; j += 256) lh[j] = 0u;
    if (t == 0) ccount = 0u;
    if (t < Cn) { lcut[t] = 0u; cls_cnt[t] = 0u; cls_pos[t] = 0u; }
    __syncthreads();

    const float* base = logits + (size_t)b * Cn * Sn;
    const float4* s0 = (const float4*)base;
    const float4* s1 = (const float4*)(base + Sn);
    const float4* s2 = (const float4*)(base + 2 * Sn);
    const float4* s3 = (const float4*)(base + 3 * Sn);
    const int qs = blockIdx.x * (PB / 4);
    #pragma unroll
    for (int it = 0; it < PB / 4 / 256; ++it) {   // 4 iterations
        int q = qs + it * 256 + t;
        float4 v0 = s0[q], v1 = s1[q], v2 = s2[q], v3 = s3[q];
        const float* a0 = &v0.x; const float* a1 = &v1.x;
        const float* a2 = &v2.x; const float* a3 = &v3.x;
        #pragma unroll
        for (int k = 0; k < 4; ++k) {
            int cm; float p;
            softmax_argmax4(a0[k], a1[k], a2[k], a3[k], &cm, &p);
            if (p > THRf) {
                unsigned int ub = __float_as_uint(p);
                atomicAdd(&lh[cm * NBINS + bin_of_bits(ub)], 1u);
                unsigned int pos = atomicAdd(&ccount, 1u);
                // idx fits in 21 bits (Sn = 2^21); class in bits 21-22
                buf[pos] = make_uint2(ub, (unsigned int)(q * 4 + k) | ((unsigned int)cm << 21));
            }
        }
    }
    __syncthreads();

    // phase 2: wave w computes cutoff for class w. 64 lanes x 17 bins = 1088 >= 1025.
    {
        const int wave = t >> 6, lane = t & 63;
        const unsigned int* h = &lh[wave * NBINS];
        const int lo = lane * 17;
        unsigned int cs = 0;
        #pragma unroll
        for (int k = 0; k < 17; ++k) {
            int bin = lo + k;
            if (bin < NBINS) cs += h[bin];
        }
        unsigned int S = cs;  // inclusive suffix sum over lanes (lane..63)
        #pragma unroll
        for (int off = 1; off < 64; off <<= 1) {
            unsigned int v = __shfl_down(S, off, 64);
            if (lane + off < 64) S += v;
        }
        unsigned int suf = S - cs;  // sum of bins strictly above this lane's chunk
        if (S >= NPTS && suf < NPTS) {
            unsigned int acc = suf;
            int hi = min(lo + 16, NBINS - 1);
            for (int bin = hi; bin >= lo; --bin) {
                acc += h[bin];
                if (acc >= NPTS) { lcut[wave] = (unsigned int)bin; break; }
            }
        }
        // if class total < 32, no lane fires and lcut stays 0 (emit all)
    }
    __syncthreads();

    // phase 3a: count passing entries per class (LDS atomics only)
    const unsigned int n = ccount;
    for (unsigned int j = t; j < n; j += 256) {
        uint2 e = buf[j];
        unsigned int cm = e.y >> 21;
        if ((unsigned int)bin_of_bits(e.x) >= lcut[cm])
            atomicAdd(&cls_cnt[cm], 1u);
    }
    __syncthreads();
    // phase 3b: one global reservation per (block, class)
    if (t < Cn && cls_cnt[t] > 0)
        cls_base[t] = atomicAdd(&cnt[b * Cn + t], cls_cnt[t]);
    __syncthreads();
    // phase 3c: write entries at reserved offsets
    for (unsigned int j = t; j < n; j += 256) {
        uint2 e = buf[j];
        unsigned int cm = e.y >> 21;
        if ((unsigned int)bin_of_bits(e.x) >= lcut[cm]) {
            unsigned int pos = cls_base[cm] + atomicAdd(&cls_pos[cm], 1u);
            if (pos < (unsigned int)cap)
                cand[(size_t)(b * Cn + cm) * cap + pos] =
                    make_uint2(e.x, e.y & 0x1FFFFFu);
        }
    }
}

// Finish: per batch (2 blocks), for each class: superset hist -> exact global
// cutoff -> filter (~40 entries) -> O(m^2) exact rank -> top-32; then compact
// in class order [1,2,3,0], unravel coords, pad with -1/0, write output.
// Correctness: bins strictly above the superset-derived cutoff are complete in
// the superset (every such entry has global rank < 32, and all rank<32 entries
// survive every block's local cutoff), so ranking within the filtered set is
// exact for the top-32. validn = min(n, 32) is exact because entries are only
// dropped when >=32 locally-greater entries exist.
__global__ __launch_bounds__(256) void finish_kernel(const unsigned int* __restrict__ cnt,
                                                     const uint2* __restrict__ cand,
                                                     int cap,
                                                     int* __restrict__ out) {
    __shared__ unsigned int lh[NBINS];
    __shared__ uint2 fbuf[FCAP];
    __shared__ unsigned int s_m, s_T;
    __shared__ uint2 topkL[Cn * NPTS];
    __shared__ int vn_s[Cn];
    __shared__ int pre[Cn + 1];
    const int b = blockIdx.x;
    const int t = threadIdx.x;

    for (int c = 0; c < Cn; ++c) {
        const int bc = b * Cn + c;
        const int n = min((int)cnt[bc], cap);
        for (int j = t; j < NBINS; j += 256) lh[j] = 0u;
        if (t == 0) { s_m = 0u; s_T = 0u; }
        __syncthreads();
        const uint2* src = cand + (size_t)bc * cap;
        for (int j = t; j < n; j += 256)
            atomicAdd(&lh[bin_of_bits(src[j].x)], 1u);
        __syncthreads();
        if (t < 64) {  // wave 0: cutoff scan
            const int lane = t;
            const int lo = lane * 17;
            unsigned int cs = 0;
            #pragma unroll
            for (int k = 0; k < 17; ++k) {
                int bin = lo + k;
                if (bin < NBINS) cs += lh[bin];
            }
            unsigned int S = cs;
            #pragma unroll
            for (int off = 1; off < 64; off <<= 1) {
                unsigned int v = __shfl_down(S, off, 64);
                if (lane + off < 64) S += v;
            }
            unsigned int suf = S - cs;
            if (S >= NPTS && suf < NPTS) {
                unsigned int acc = suf;
                int hi = min(lo + 16, NBINS - 1);
                for (int bin = hi; bin >= lo; --bin) {
                    acc += lh[bin];
                    if (acc >= NPTS) { s_T = (unsigned int)bin; break; }
                }
            }
        }
        __syncthreads();
        const unsigned int T = s_T;
        for (int j = t; j < n; j += 256) {
            uint2 e = src[j];
            if ((unsigned int)bin_of_bits(e.x) >= T) {
                unsigned int pos = atomicAdd(&s_m, 1u);
                if (pos < FCAP) fbuf[pos] = e;
            }
        }
        __syncthreads();
        const int m = min((int)s_m, FCAP);
        const int vn = min(n, NPTS);
        if (t == 0) vn_s[c] = vn;
        for (int i = t; i < m; i += 256) {
            uint2 e = fbuf[i];
            int rank = 0;
            for (int j = 0; j < m; ++j) {
                uint2 o = fbuf[j];
                rank += (int)((o.x > e.x) || (o.x == e.x && o.y < e.y));
            }
            if (rank < vn) topkL[c * NPTS + rank] = e;
        }
        __syncthreads();
    }

    // compact + emit (class order [1,2,3,0])
    if (t == 0) {
        int acc = 0;
        for (int oc = 0; oc < Cn; ++oc) {
            pre[oc] = acc;
            acc += vn_s[(oc + 1) & 3];
        }
        pre[Cn] = acc;
    }
    __syncthreads();
    if (t < Cn * NPTS) {  // 128 output slots per batch
        const int j = t;
        int label = -1, z = 0, y = 0, x = 0;
        if (j < pre[Cn]) {
            int oc = 0;
            while (j >= pre[oc + 1]) ++oc;
            int c = (oc + 1) & 3;
            int r = j - pre[oc];
            uint2 e = topkL[c * NPTS + r];
            int idx = (int)e.y;
            z = idx >> 14;          // idx / (128*128)
            y = (idx >> 7) & 127;   // (idx / 128) % 128
            x = idx & 127;          // idx % 128
            label = c;
        }
        int* coords = out;                       // 2*128*3 = 768 ints
        int* labels = out + Bn * Cn * NPTS * 3;  // then 2*128 = 256 ints
        int base = b * Cn * NPTS + j;
        coords[base * 3 + 0] = z;
        coords[base * 3 + 1] = y;
        coords[base * 3 + 2] = x;
        labels[base] = label;
    }
}

extern "C" void kernel_launch(void* const* d_in, const int* in_sizes, int n_in,
                              void* d_out, int out_size, void* d_ws, size_t ws_size,
                              hipStream_t stream) {
    const float* logits = (const float*)d_in[0];
    int* out = (int*)d_out;

    // Workspace layout
    unsigned int* cnt = (unsigned int*)d_ws;             // 8 u32
    uint2* cand = (uint2*)(cnt + 8);                     // 8 * cap uint2 (8-aligned: 32 B offset)
    size_t fixed = (size_t)((char*)cand - (char*)d_ws);
    int cap = (int)((ws_size - fixed) / (Bn * Cn * sizeof(uint2)));
    if (cap > (1 << 18)) cap = 1 << 18;   // 256k entries/bc >> the ~20k expected
    if (cap < 4096) cap = 4096;

    // Zero the 8 append counters only (capture-legal, stream-ordered)
    hipMemsetAsync(cnt, 0, Bn * Cn * sizeof(unsigned int), stream);

    dim3 grid(Sn / PB, Bn);   // (512, 2)
    fused_kernel<<<grid, 256, 0, stream>>>(logits, cnt, cand, cap);
    finish_kernel<<<Bn, 256, 0, stream>>>(cnt, cand, cap, out);
}

// Round 5
// 122.720 us; speedup vs baseline: 7.5184x; 1.8868x over previous
//
#include <hip/hip_runtime.h>
#include <stdint.h>

// Problem constants (reference: B=2, C=4, SPATIAL=(128,128,128), N_PTS=32, THR=0.5)
#define Bn 2
#define Cn 4
#define Sn (128 * 128 * 128)   // 2^21 voxels per (b,c)
#define NPTS 32
#define NBINS 1025             // probs in (0.5, 1] -> one binade; (bits-0x3F000000)>>13 in [0,1024]
#define THRf 0.5f
#define PB 4096                // voxels per block in the fused pass
#define FCAP 2048              // LDS filtered-candidate cap in select3

__device__ __forceinline__ int bin_of_bits(unsigned int u) {
    return (int)((u - 0x3F000000u) >> 13);
}

// Softmax over the 4 classes at one voxel given the 4 logits; returns argmax class and its prob.
// Mirrors jax.nn.softmax: exp(x - max) / sum(exp(x - max)), sequential sum c=0..3.
// (Only the argmax class can have p > 0.5 since probs sum to 1.)
__device__ __forceinline__ void softmax_argmax4(float l0, float l1, float l2, float l3,
                                                int* cm_out, float* p_out) {
    float m = fmaxf(fmaxf(l0, l1), fmaxf(l2, l3));
    float e0 = expf(l0 - m);
    float e1 = expf(l1 - m);
    float e2 = expf(l2 - m);
    float e3 = expf(l3 - m);
    float s = ((e0 + e1) + e2) + e3;
    float em = e0; int cm = 0;
    if (e1 > em) { em = e1; cm = 1; }
    if (e2 > em) { em = e2; cm = 2; }
    if (e3 > em) { em = e3; cm = 3; }
    *cm_out = cm;
    *p_out = em / s;   // identical float division to reference's p_c = e_c / s
}

// Fused single-read pass:
//  phase 1: stream 4096 voxels (float4 x 4 class streams), cache candidates (p>0.5)
//           in LDS, build per-class local radix histogram in LDS.
//  phase 2: per-class local cutoff (wave w handles class w; shuffle suffix-scan).
//           Entries below the local cutoff have >=32 strictly-greater local entries
//           -> global rank >= 32 -> safe to drop. Union over blocks is a superset
//           of the global top-32 per (b,c).
//  phase 3: block-aggregated emit — count passing entries per class, ONE global
//           atomicAdd per (block,class) to reserve a range, then write entries.
__global__ __launch_bounds__(256) void fused_kernel(const float* __restrict__ logits,
                                                    unsigned int* __restrict__ cnt,
                                                    uint2* __restrict__ cand,
                                                    int cap) {
    __shared__ unsigned int lh[Cn * NBINS];   // 16.4 KB
    __shared__ uint2 buf[PB];                 // 32 KB  (max 1 candidate per voxel)
    __shared__ unsigned int ccount;
    __shared__ unsigned int lcut[Cn];
    __shared__ unsigned int cls_cnt[Cn], cls_base[Cn], cls_pos[Cn];
    const int b = blockIdx.y;
    const int t = threadIdx.x;
    for (int j = t; j < Cn * NBINS; j += 256) lh[j] = 0u;
    if (t == 0) ccount = 0u;
    if (t < Cn) { lcut[t] = 0u; cls_cnt[t] = 0u; cls_pos[t] = 0u; }
    __syncthreads();

    const float* base = logits + (size_t)b * Cn * Sn;
    const float4* s0 = (const float4*)base;
    const float4* s1 = (const float4*)(base + Sn);
    const float4* s2 = (const float4*)(base + 2 * Sn);
    const float4* s3 = (const float4*)(base + 3 * Sn);
    const int qs = blockIdx.x * (PB / 4);
    #pragma unroll
    for (int it = 0; it < PB / 4 / 256; ++it) {   // 4 iterations
        int q = qs + it * 256 + t;
        float4 v0 = s0[q], v1 = s1[q], v2 = s2[q], v3 = s3[q];
        const float* a0 = &v0.x; const float* a1 = &v1.x;
        const float* a2 = &v2.x; const float* a3 = &v3.x;
        #pragma unroll
        for (int k = 0; k < 4; ++k) {
            int cm; float p;
            softmax_argmax4(a0[k], a1[k], a2[k], a3[k], &cm, &p);
            if (p > THRf) {
                unsigned int ub = __float_as_uint(p);
                atomicAdd(&lh[cm * NBINS + bin_of_bits(ub)], 1u);
                unsigned int pos = atomicAdd(&ccount, 1u);
                // idx fits in 21 bits (Sn = 2^21); class in bits 21-22
                buf[pos] = make_uint2(ub, (unsigned int)(q * 4 + k) | ((unsigned int)cm << 21));
            }
        }
    }
    __syncthreads();

    // phase 2: wave w computes cutoff for class w. 64 lanes x 17 bins = 1088 >= 1025.
    {
        const int wave = t >> 6, lane = t & 63;
        const unsigned int* h = &lh[wave * NBINS];
        const int lo = lane * 17;
        unsigned int cs = 0;
        #pragma unroll
        for (int k = 0; k < 17; ++k) {
            int bin = lo + k;
            if (bin < NBINS) cs += h[bin];
        }
        unsigned int S = cs;  // inclusive suffix sum over lanes (lane..63)
        #pragma unroll
        for (int off = 1; off < 64; off <<= 1) {
            unsigned int v = __shfl_down(S, off, 64);
            if (lane + off < 64) S += v;
        }
        unsigned int suf = S - cs;  // sum of bins strictly above this lane's chunk
        if (S >= NPTS && suf < NPTS) {
            unsigned int acc = suf;
            int hi = min(lo + 16, NBINS - 1);
            for (int bin = hi; bin >= lo; --bin) {
                acc += h[bin];
                if (acc >= NPTS) { lcut[wave] = (unsigned int)bin; break; }
            }
        }
        // if class total < 32, no lane fires and lcut stays 0 (emit all)
    }
    __syncthreads();

    // phase 3a: count passing entries per class (LDS atomics only)
    const unsigned int n = ccount;
    for (unsigned int j = t; j < n; j += 256) {
        uint2 e = buf[j];
        unsigned int cm = e.y >> 21;
        if ((unsigned int)bin_of_bits(e.x) >= lcut[cm])
            atomicAdd(&cls_cnt[cm], 1u);
    }
    __syncthreads();
    // phase 3b: one global reservation per (block, class)
    if (t < Cn && cls_cnt[t] > 0)
        cls_base[t] = atomicAdd(&cnt[b * Cn + t], cls_cnt[t]);
    __syncthreads();
    // phase 3c: write entries at reserved offsets
    for (unsigned int j = t; j < n; j += 256) {
        uint2 e = buf[j];
        unsigned int cm = e.y >> 21;
        if ((unsigned int)bin_of_bits(e.x) >= lcut[cm]) {
            unsigned int pos = cls_base[cm] + atomicAdd(&cls_pos[cm], 1u);
            if (pos < (unsigned int)cap)
                cand[(size_t)(b * Cn + cm) * cap + pos] =
                    make_uint2(e.x, e.y & 0x1FFFFFu);
        }
    }
}

// Wide exact-top-32 pass: ONE BLOCK PER (b,c), 1024 threads (16 waves) so the
// ~18k-entry superset scan is ~18 coalesced iterations with real latency hiding
// (round 4's 2-block finish was latency-bound at 124 us).
// Correctness: bins strictly above the superset-derived cutoff are complete in
// the superset (every such entry has global rank < 32, and all rank<32 entries
// survive every block's local cutoff), so ranking within the filtered set is
// exact for the top-32. validn = min(n, 32) is exact because entries are only
// dropped when >=32 locally-greater entries exist.
__global__ __launch_bounds__(1024) void select3(const unsigned int* __restrict__ cnt,
                                                const uint2* __restrict__ cand,
                                                int cap,
                                                unsigned int* __restrict__ validn,
                                                uint2* __restrict__ topk) {
    __shared__ unsigned int lh[NBINS];
    __shared__ uint2 fbuf[FCAP];
    __shared__ unsigned int s_m, s_T;
    const int bc = blockIdx.x, t = threadIdx.x;
    const int n = min((int)cnt[bc], cap);
    for (int j = t; j < NBINS; j += 1024) lh[j] = 0u;
    if (t == 0) { s_m = 0u; s_T = 0u; }
    __syncthreads();
    const uint2* src = cand + (size_t)bc * cap;
    for (int j = t; j < n; j += 1024)
        atomicAdd(&lh[bin_of_bits(src[j].x)], 1u);
    __syncthreads();
    if (t < 64) {  // wave 0: cutoff scan (64 lanes x 17 bins >= 1025)
        const int lane = t;
        const int lo = lane * 17;
        unsigned int cs = 0;
        #pragma unroll
        for (int k = 0; k < 17; ++k) {
            int bin = lo + k;
            if (bin < NBINS) cs += lh[bin];
        }
        unsigned int S = cs;
        #pragma unroll
        for (int off = 1; off < 64; off <<= 1) {
            unsigned int v = __shfl_down(S, off, 64);
            if (lane + off < 64) S += v;
        }
        unsigned int suf = S - cs;
        if (S >= NPTS && suf < NPTS) {
            unsigned int acc = suf;
            int hi = min(lo + 16, NBINS - 1);
            for (int bin = hi; bin >= lo; --bin) {
                acc += lh[bin];
                if (acc >= NPTS) { s_T = (unsigned int)bin; break; }
            }
        }
    }
    __syncthreads();
    const unsigned int T = s_T;
    for (int j = t; j < n; j += 1024) {
        uint2 e = src[j];
        if ((unsigned int)bin_of_bits(e.x) >= T) {
            unsigned int pos = atomicAdd(&s_m, 1u);
            if (pos < FCAP) fbuf[pos] = e;
        }
    }
    __syncthreads();
    const int m = min((int)s_m, FCAP);
    const int vn = min(n, NPTS);
    if (t == 0) validn[bc] = (unsigned int)vn;
    // m is ~32 + ties-in-cutoff-bin (tiny); exact rank, jax tie-break (lower idx wins)
    for (int i = t; i < m; i += 1024) {
        uint2 e = fbuf[i];
        int rank = 0;
        for (int j = 0; j < m; ++j) {
            uint2 o = fbuf[j];
            rank += (int)((o.x > e.x) || (o.x == e.x && o.y < e.y));
        }
        if (rank < vn) topk[bc * NPTS + rank] = e;
    }
}

// Compact per-batch in class order [1,2,3,0], unravel coords, pad with -1/0.
// Output layout: coords int32 (2,128,3) flat, then labels int32 (2,128).
__global__ void emit_kernel(const uint2* __restrict__ topk,
                            const unsigned int* __restrict__ validn,
                            int* __restrict__ out) {
    const int b = blockIdx.x;
    __shared__ int pre[Cn + 1];
    if (threadIdx.x == 0) {
        int acc = 0;
        for (int oc = 0; oc < Cn; ++oc) {
            pre[oc] = acc;
            int c = (oc + 1) & 3;  // order = [1,2,3,0]
            acc += (int)validn[b * Cn + c];
        }
        pre[Cn] = acc;
    }
    __syncthreads();
    const int j = threadIdx.x;  // 0..127
    int label = -1, z = 0, y = 0, x = 0;
    if (j < pre[Cn]) {
        int oc = 0;
        while (j >= pre[oc + 1]) ++oc;
        int c = (oc + 1) & 3;
        int r = j - pre[oc];
        uint2 e = topk[(b * Cn + c) * NPTS + r];
        int idx = (int)e.y;
        z = idx >> 14;          // idx / (128*128)
        y = (idx >> 7) & 127;   // (idx / 128) % 128
        x = idx & 127;          // idx % 128
        label = c;
    }
    int* coords = out;                       // 2*128*3 = 768 ints
    int* labels = out + Bn * Cn * NPTS * 3;  // then 2*128 = 256 ints
    int base = b * Cn * NPTS + j;
    coords[base * 3 + 0] = z;
    coords[base * 3 + 1] = y;
    coords[base * 3 + 2] = x;
    labels[base] = label;
}

extern "C" void kernel_launch(void* const* d_in, const int* in_sizes, int n_in,
                              void* d_out, int out_size, void* d_ws, size_t ws_size,
                              hipStream_t stream) {
    const float* logits = (const float*)d_in[0];
    int* out = (int*)d_out;

    // Workspace layout
    unsigned int* cnt = (unsigned int*)d_ws;             // 8 u32
    unsigned int* validn = cnt + Bn * Cn;                // 8 u32
    uint2* topk = (uint2*)(validn + Bn * Cn);            // 8*32 uint2 = 2048 B (8-aligned)
    uint2* cand = topk + Bn * Cn * NPTS;                 // 8 * cap uint2
    size_t fixed = (size_t)((char*)cand - (char*)d_ws);
    int cap = (int)((ws_size - fixed) / (Bn * Cn * sizeof(uint2)));
    if (cap > (1 << 18)) cap = 1 << 18;   // 256k entries/bc >> the ~20k expected
    if (cap < 4096) cap = 4096;

    // Zero the 8 append counters only (capture-legal, stream-ordered)
    hipMemsetAsync(cnt, 0, Bn * Cn * sizeof(unsigned int), stream);

    dim3 grid(Sn / PB, Bn);   // (512, 2)
    fused_kernel<<<grid, 256, 0, stream>>>(logits, cnt, cand, cap);
    select3<<<Bn * Cn, 1024, 0, stream>>>(cnt, cand, cap, validn, topk);
    emit_kernel<<<Bn, 128, 0, stream>>>(topk, validn, out);
}